// Round 11
// baseline (947.883 us; speedup 1.0000x reference)
//
#include <hip/hip_runtime.h>
#include <math.h>

#define B_ 16
#define L_ 720
#define C_ 128
#define H_ 96
#define F2_ 49
#define K_ 8
#define S_ 8
#define OUT_ 833          // F2*(2K+1)
#define SEQLEN 816        // L + H
#define NF 361            // rfft bins for L=720

__device__ __forceinline__ float2 cmulp(float2 a, float2 w) {   // a * w (complex)
  return make_float2(a.x*w.x - a.y*w.y, a.x*w.y + a.y*w.x);
}

// Per-wave LDS fence: all my LDS ops done, and no compiler reordering across it (rule #18).
#define WSYNC() do { asm volatile("s_waitcnt lgkmcnt(0)" ::: "memory"); __builtin_amdgcn_sched_barrier(0); } while (0)

// W5^m = e^{+2*pi*i*m/5}
__device__ __constant__ float W5X[5] = {1.f, 0.30901699437494742f, -0.80901699437494745f, -0.80901699437494745f, 0.30901699437494742f};
__device__ __constant__ float W5Y[5] = {0.f, 0.95105651629515357f, 0.58778525229247312f, -0.58778525229247312f, -0.95105651629515357f};

// DFT-8, positive exponent (omega = e^{+i*pi/4}) — verified in R9.
__device__ __forceinline__ void dft8_pos(const float2 zin[8], float2 X[8]) {
  const float RH = 0.70710678118654752440f;
  const float2 A0 = make_float2(zin[0].x+zin[4].x, zin[0].y+zin[4].y);
  const float2 A1 = make_float2(zin[0].x-zin[4].x, zin[0].y-zin[4].y);
  const float2 A2 = make_float2(zin[2].x+zin[6].x, zin[2].y+zin[6].y);
  const float2 A3 = make_float2(zin[2].x-zin[6].x, zin[2].y-zin[6].y);
  const float2 A4 = make_float2(zin[1].x+zin[5].x, zin[1].y+zin[5].y);
  const float2 A5 = make_float2(zin[1].x-zin[5].x, zin[1].y-zin[5].y);
  const float2 A6 = make_float2(zin[3].x+zin[7].x, zin[3].y+zin[7].y);
  const float2 A7 = make_float2(zin[3].x-zin[7].x, zin[3].y-zin[7].y);
  const float2 B0 = make_float2(A0.x+A2.x, A0.y+A2.y);
  const float2 B1 = make_float2(A0.x-A2.x, A0.y-A2.y);
  const float2 B2 = make_float2(A4.x+A6.x, A4.y+A6.y);
  const float2 B3 = make_float2(A4.x-A6.x, A4.y-A6.y);
  X[0] = make_float2(B0.x+B2.x, B0.y+B2.y);
  X[4] = make_float2(B0.x-B2.x, B0.y-B2.y);
  X[2] = make_float2(B1.x - B3.y, B1.y + B3.x);   // B1 + i*B3
  X[6] = make_float2(B1.x + B3.y, B1.y - B3.x);   // B1 - i*B3
  const float2 CI   = make_float2(-A3.y, A3.x);   // i*A3
  const float2 W1s1 = make_float2((A5.x - A5.y)*RH, (A5.x + A5.y)*RH);   // w^1*A5
  const float2 W3s1 = make_float2((-A5.x - A5.y)*RH, (A5.x - A5.y)*RH);  // w^3*A5
  const float2 W1s3 = make_float2((A7.x - A7.y)*RH, (A7.x + A7.y)*RH);   // w^1*A7
  const float2 W3s3 = make_float2((-A7.x - A7.y)*RH, (A7.x - A7.y)*RH);  // w^3*A7
  X[1] = make_float2(A1.x + CI.x + W1s1.x + W3s3.x, A1.y + CI.y + W1s1.y + W3s3.y);
  X[5] = make_float2(A1.x + CI.x - W1s1.x - W3s3.x, A1.y + CI.y - W1s1.y - W3s3.y);
  X[3] = make_float2(A1.x - CI.x + W3s1.x + W1s3.x, A1.y - CI.y + W3s1.y + W1s3.y);
  X[7] = make_float2(A1.x - CI.x - W3s1.x - W1s3.x, A1.y - CI.y - W3s1.y - W1s3.y);
}

// ---------------------------------------------------------------- K0: twiddle table (once per launch)
__global__ __launch_bounds__(256) void k0_tab(float2* __restrict__ wtab_g) {
  for (int k = threadIdx.x; k < L_; k += 256) {
    double ang = (double)k * 0.008726646259971647884;   // 2*pi/720
    wtab_g[k] = make_float2((float)cos(ang), (float)sin(ang));
  }
}

// ---------------------------------------------------------------- K1: normalize + forward rfft, 2 adjacent channels per block
__global__ __launch_bounds__(256) void k1_fused(const float* __restrict__ x,
                                                const float* __restrict__ yh,
                                                const float2* __restrict__ wtab_g,
                                                float* __restrict__ seq,
                                                float* __restrict__ mu_g,
                                                float* __restrict__ std_g,
                                                float2* __restrict__ Rc) {
  const int bc0 = blockIdx.x * 2;       // channels bc0, bc0+1 (adjacent c -> float2 loads)
  const int b = bc0 >> 7, c0 = bc0 & 127;
  const int tid = threadIdx.x;
  __shared__ float xrow[2][L_];
  __shared__ float yrow[2][H_];
  __shared__ float2 wt[L_];
  __shared__ float red[4];

  const float* xb = x + (size_t)b * L_ * C_ + c0;
  for (int l = tid; l < L_; l += 256) {
    const float2 v = *(const float2*)&xb[(size_t)l * C_];
    xrow[0][l] = v.x; xrow[1][l] = v.y;
  }
  const float* yb = yh + (size_t)b * H_ * C_ + c0;
  if (tid < H_) {
    const float2 v = *(const float2*)&yb[(size_t)tid * C_];
    yrow[0][tid] = v.x; yrow[1][tid] = v.y;
  }
  for (int k = tid; k < L_; k += 256) wt[k] = wtab_g[k];
  __syncthreads();

  for (int ch = 0; ch < 2; ++ch) {
    float s = 0.f;
    for (int l = tid; l < L_; l += 256) s += xrow[ch][l];
    for (int off = 32; off; off >>= 1) s += __shfl_down(s, off, 64);
    if ((tid & 63) == 0) red[tid >> 6] = s;
    __syncthreads();
    const float mu = (red[0] + red[1] + red[2] + red[3]) * (1.0f / L_);
    __syncthreads();
    float vs = 0.f;
    for (int l = tid; l < L_; l += 256) { float d = xrow[ch][l] - mu; vs += d * d; }
    for (int off = 32; off; off >>= 1) vs += __shfl_down(vs, off, 64);
    if ((tid & 63) == 0) red[tid >> 6] = vs;
    __syncthreads();
    const float stdv = sqrtf((red[0] + red[1] + red[2] + red[3]) * (1.0f / L_) + 1e-8f);
    const float inv = 1.0f / stdv;
    if (tid == 0) { mu_g[bc0 + ch] = mu; std_g[bc0 + ch] = stdv; }
    __syncthreads();                     // red reused next ch; also xrow rewrite guard
    float* sq = seq + (size_t)(bc0 + ch) * SEQLEN;
    for (int l = tid; l < L_; l += 256) { const float v = (xrow[ch][l] - mu) * inv; xrow[ch][l] = v; sq[l] = v; }
    if (tid < H_) sq[L_ + tid] = (yrow[ch][tid] - mu) * inv;
    __syncthreads();
  }

  for (int u = tid; u < 2 * NF; u += 256) {   // rfft (negative exponent), from normalized LDS rows
    const int row = u / NF, f = u - row * NF;
    float re = 0.f, im = 0.f;
    int m = 0;
    const float* xr = xrow[row];
    for (int l = 0; l < L_; ++l) {
      const float v = xr[l];
      const float2 w = wt[m];
      re = fmaf(v, w.x, re);
      im = fmaf(-v, w.y, im);
      m += f; if (m >= L_) m -= L_;
    }
    Rc[(size_t)(bc0 + row) * NF + f] = make_float2(re, im);
  }
}

// ---------------------------------------------------------------- K2: per-wave spectral product + real-packed 360-pt IFFT, 2 pairs/wave/iter
// cc (real, len 720) via z[n] = cc[2n] + i*cc[2n+1] = IDFT360(Z); Z from Hermitian P (see R9).
// Stage-1 = 90 tasks (pair, K2) over 64 lanes in 2 passes (R11: was 45 lanes x 2 serial pairs).
// NOTE: __launch_bounds__(256,2) is load-bearing (R4/R6: tighter bounds force scratch spills).
__global__ __launch_bounds__(256, 2) void k2_fft(const float2* __restrict__ Rc,
                                                 const float2* __restrict__ wtab_g,
                                                 float* __restrict__ r_arr,
                                                 int* __restrict__ t_arr) {
  // XCD-aware bijective swizzle (T1): grid = 9216 = 8 * 1152 -> each XCD gets 2 contiguous batches.
  const int phys = blockIdx.x;
  int idx = (phys & 7) * 1152 + (phys >> 3);
  const int b = idx / 576;
  idx -= b * 576;
  int g = 0;
  while (true) { const int cnt = (8 - g) << 4; if (idx < cnt) break; idx -= cnt; ++g; }
  const int rows = 8 - g;
  const int c1 = (g << 4) + idx / rows;
  const int c2t = g + idx % rows;
  const int c2base = c2t << 4;
  const int tid = threadIdx.x;
  const int wid = tid >> 6, lane = tid & 63;

  __shared__ float2 r1c[NF];
  __shared__ float2 t9[81];                      // W9^{a*c} at [9a+c]
  __shared__ float2 t45[45];                     // W45^{b*c} at [9b+c]
  __shared__ float2 Yw[4][2][360];               // per-wave, per-pair stage-1 out [n1*45+K2]
  __shared__ __align__(16) float ccw[4][2][728]; // per-wave, per-pair cc row

  for (int f = tid; f < NF; f += 256) r1c[f] = Rc[((size_t)(b * C_ + c1)) * NF + f];
  for (int i = tid; i < 81; i += 256) { int a = i / 9, c = i % 9; t9[i] = wtab_g[80 * ((a * c) % 9)]; }
  for (int i = tid; i < 45; i += 256) { int bb = i / 9, c = i % 9; t45[i] = wtab_g[16 * bb * c]; }
  __syncthreads();                   // the only block-wide barrier

  const float SCALE = 1.0f / 518400.0f;   // 1/720^2

  for (int it = 0; it < 2; ++it) {
    const int c2A = c2base + (wid << 2) + 2 * it;    // pair A; pair B = c2A+1
    if (c2A + 1 < c1) continue;      // both pairs below diagonal: nothing would be emitted
    const float2* R2A = Rc + ((size_t)(b * C_ + c2A)) * NF;   // L2-hot after swizzle
    const float2* R2B = R2A + NF;

    // ---- stage 1: 90 tasks (pair, K2) over 64 lanes, 2 passes. Z on the fly + DFT-8 + W360 twiddle.
#pragma unroll
    for (int pass = 0; pass < 2; ++pass) {
      const int t = lane + (pass << 6);
      if (t < 90) {
        const int pr = (t >= 45) ? 1 : 0;
        const int K2 = t - 45 * pr;
        const float2* R2 = pr ? R2B : R2A;
        float2 zin[8];
#pragma unroll
        for (int q1 = 0; q1 < 8; ++q1) {
          const int k = 45 * q1 + K2;              // in [0, 360)
          const int fB = 360 - k;                  // in [1, 360]
          const float2 a1 = r1c[k];
          const float2 a2 = r1c[fB];
          const float2 w  = wtab_g[k];
          const float2 b1 = R2[k];
          const float2 b2 = R2[fB];
          const float2 pA = make_float2(a1.x*b1.x + a1.y*b1.y, a1.y*b1.x - a1.x*b1.y);
          float2 pB = make_float2(a2.x*b2.x + a2.y*b2.y, a2.y*b2.x - a2.x*b2.y);
          pB.y = (k == 0) ? pB.y : -pB.y;          // conj for k>=1
          const float2 E = make_float2(pA.x + pB.x, pA.y + pB.y);
          const float2 O = make_float2(pA.x - pB.x, pA.y - pB.y);
          const float2 Ow = cmulp(O, w);
          zin[q1] = make_float2(E.x - Ow.y, E.y + Ow.x);   // E + i*Ow
        }
        float2 X[8];
        dft8_pos(zin, X);
        int m = 0;                                 // m = 2*K2*n1 <= 616: no mod needed
#pragma unroll
        for (int n1 = 0; n1 < 8; ++n1) {
          Yw[wid][pr][n1 * 45 + K2] = cmulp(X[n1], wtab_g[m]);   // exact W360^{K2*n1}
          m += 2 * K2;
        }
      }
    }
    WSYNC();   // my wave's Yw writes visible to my wave's stage-2 reads

    // ---- stage 2: DFT-45 per n1-row (9x5 CT), complex out, both pairs with shared reg tables.
    {
      const int n1 = lane >> 3;
      const int cq = lane & 7;
      const int nci = (cq == 0) ? 2 : 1;
      int cvals[2] = { cq, 8 };

      float2 T9r[2][9], T45r[2][5];
#pragma unroll
      for (int ci = 0; ci < 2; ++ci) if (ci < nci) {
        const int c = cvals[ci];
#pragma unroll
        for (int a = 0; a < 9; ++a) T9r[ci][a] = t9[9 * a + c];
#pragma unroll
        for (int bq = 0; bq < 5; ++bq) T45r[ci][bq] = t45[9 * bq + c];
      }

#pragma unroll
      for (int pp = 0; pp < 2; ++pp) {
        const float2* Yrow = &Yw[wid][pp][n1 * 45];
        float yr[2][5], yi[2][5];
#pragma unroll
        for (int ci = 0; ci < 2; ++ci)
#pragma unroll
          for (int d = 0; d < 5; ++d) { yr[ci][d] = 0.f; yi[ci][d] = 0.f; }

#pragma unroll
        for (int bq = 0; bq < 5; ++bq) {
          float2 z[9];
#pragma unroll
          for (int a = 0; a < 9; ++a) z[a] = Yrow[5 * a + bq];
#pragma unroll
          for (int ci = 0; ci < 2; ++ci) if (ci < nci) {
            float ur = 0.f, ui = 0.f;
#pragma unroll
            for (int a = 0; a < 9; ++a) {
              ur += z[a].x * T9r[ci][a].x - z[a].y * T9r[ci][a].y;
              ui += z[a].x * T9r[ci][a].y + z[a].y * T9r[ci][a].x;
            }
            const float2 tw = T45r[ci][bq];
            const float vr = ur * tw.x - ui * tw.y;
            const float vi = ur * tw.y + ui * tw.x;
#pragma unroll
            for (int d = 0; d < 5; ++d) {
              const int m = (bq * d) % 5;                   // compile-time
              yr[ci][d] += vr * W5X[m] - vi * W5Y[m];
              yi[ci][d] += vr * W5Y[m] + vi * W5X[m];
            }
          }
        }
        float2* cc2 = (float2*)(&ccw[wid][pp][0]);
#pragma unroll
        for (int ci = 0; ci < 2; ++ci) if (ci < nci) {
          const int c = cvals[ci];
#pragma unroll
          for (int d = 0; d < 5; ++d) {
            const int n2 = c + 9 * d;
            cc2[n1 + 8 * n2] = make_float2(yr[ci][d], yi[ci][d]);   // cc[2n], cc[2n+1]
          }
        }
      }
    }
    WSYNC();   // ccw writes visible to my wave's scans

    // ---- merged peak scans, half-wave per row (lanes 0-31: pair A, 32-63: pair B).
    {
      const int half = lane >> 5, sl = lane & 31;
      const int c2h = c2A + half;
      const float* cr = ccw[wid][half];
      float bvF = 0.f; int btF = 1;
      float bvM = 0.f; int uM  = 719;      // -> t' = 1 on all-zero
      for (int i = sl; i < 719; i += 32) {
        const int u = i + 1;               // 1..719
        const float v  = fabsf(cr[u]);
        const float lf = fabsf(cr[u - 1]);
        const float rt = fabsf(cr[(u == 719) ? 0 : (u + 1)]);
        if (v >= lf && v >= rt) {
          if (u <= 718 && (v > bvF || (v == bvF && u < btF))) { bvF = v; btF = u; }
          if (u >= 2   && (v > bvM || (v == bvM && u > uM)))  { bvM = v; uM  = u; }
        }
      }
      for (int off = 16; off; off >>= 1) {
        const float ovF = __shfl_down(bvF, off, 32); const int otF = __shfl_down(btF, off, 32);
        if (ovF > bvF || (ovF == bvF && otF < btF)) { bvF = ovF; btF = otF; }
        const float ovM = __shfl_down(bvM, off, 32); const int ouM = __shfl_down(uM, off, 32);
        if (ovM > bvM || (ovM == bvM && ouM > uM)) { bvM = ovM; uM = ouM; }
      }
      if (sl == 0 && c2h >= c1) {
        const float rF = (bvF > 0.f) ? cr[btF] * SCALE : 0.f;
        const size_t o = ((size_t)(b * C_ + c1)) * C_ + c2h;
        r_arr[o] = rF; t_arr[o] = btF;
        if (c2h > c1) {
          const float rM = (bvM > 0.f) ? cr[uM] * SCALE : 0.f;
          const size_t o2 = ((size_t)(b * C_ + c2h)) * C_ + c1;
          r_arr[o2] = rM; t_arr[o2] = 720 - uM;
        }
      }
    }
    WSYNC();   // scans' ccw reads done before next it overwrites
  }
}

// ---------------------------------------------------------------- K34: leaders/softmax/filt + spectral mix + output (fused; filt/leads stay in LDS)
__global__ __launch_bounds__(256) void k34_fused(const float* __restrict__ x,
                                                 const float* __restrict__ temperature,
                                                 const float* __restrict__ cls_w,
                                                 const float* __restrict__ basic_state,
                                                 const float* __restrict__ state_bias,
                                                 const float* __restrict__ mhw,
                                                 const float* __restrict__ mhb,
                                                 const float* __restrict__ r_arr,
                                                 const int* __restrict__ t_arr,
                                                 const float* __restrict__ seq,
                                                 const float* __restrict__ mu_g,
                                                 const float* __restrict__ std_g,
                                                 const float* __restrict__ mwr,
                                                 const float* __restrict__ mwi,
                                                 const float* __restrict__ mbr,
                                                 const float* __restrict__ mbi,
                                                 float* __restrict__ out) {
  const int bc = blockIdx.x;
  const int b = bc >> 7, c = bc & 127;
  const int tid = threadIdx.x;
  __shared__ float caL[C_], rL[C_];
  __shared__ int tL[C_];
  __shared__ float xrowL[L_];
  __shared__ float cfL[K_], srL[K_], pL[S_], qL[S_ * K_], praw[S_];
  __shared__ int leadL[K_], ltL[K_];
  __shared__ float cosT[96], sinT[96];
  __shared__ float ssL[K_][H_], ynL[H_], flL[OUT_];
  __shared__ float sfr[K_][F2_], sfi[K_][F2_], yfr[F2_], yfi[F2_];
  __shared__ float catr[3 * F2_], cati[3 * F2_], ofr[F2_], ofi[F2_];

  // ---- gather inputs (k3 part + k4 tables)
  const float* xb = x + (size_t)b * L_ * C_ + c;
  for (int l = tid; l < L_; l += 256) xrowL[l] = xb[(size_t)l * C_];
  if (tid < C_) {
    const float r = r_arr[(size_t)bc * C_ + tid];
    rL[tid] = r; caL[tid] = fabsf(r);
    tL[tid] = t_arr[(size_t)bc * C_ + tid];
  }
  if (tid >= 128 && tid < 224) {
    const int h = tid - 128;
    const float ang = (float)h * (float)(6.283185307179586 / 96.0);
    cosT[h] = cosf(ang); sinT[h] = sinf(ang);
    ynL[h] = seq[(size_t)bc * SEQLEN + L_ + h];
  }
  __syncthreads();

  // ---- top-k leaders + corr softmax (serial, tiny)
  if (tid == 0) {
    const float T = temperature[0];
    float lg[K_ + 1];
    lg[0] = 1.0f / T;
    for (int k = 0; k < K_; ++k) {       // stable top-k: strict > keeps smallest index on ties
      float bvv = -1.f; int bi = 0;
      for (int jj = 0; jj < C_; ++jj) { const float v = caL[jj]; if (v > bvv) { bvv = v; bi = jj; } }
      leadL[k] = bi; ltL[k] = tL[bi];
      const float rv = rL[bi];
      srL[k] = (rv > 0.f) ? 1.f : ((rv < 0.f) ? -1.f : 0.f);
      lg[k + 1] = bvv / T;
      caL[bi] = -2.f;
    }
    float m = lg[0];
    for (int k = 1; k <= K_; ++k) m = fmaxf(m, lg[k]);
    float sum = 0.f, e[K_ + 1];
    for (int k = 0; k <= K_; ++k) { e[k] = expf(lg[k] - m); sum += e[k]; }
    const float invs = 1.0f / sum;
    for (int k = 0; k < K_; ++k) cfL[k] = e[k + 1] * invs;
  }

  // ---- p logits: 8 groups of 32 lanes
  {
    const int gg = tid >> 5, lane = tid & 31;
    float acc = 0.f;
    const float* w = cls_w + (size_t)gg * L_;
    for (int l = lane; l < L_; l += 32) acc += xrowL[l] * w[l];
    for (int off = 16; off; off >>= 1) acc += __shfl_down(acc, off, 32);
    if (lane == 0) praw[gg] = acc + state_bias[gg] + basic_state[c * S_ + gg];
  }
  __syncthreads();
  if (tid == 0) {
    float m = praw[0];
    for (int s2 = 1; s2 < S_; ++s2) m = fmaxf(m, praw[s2]);
    float sum = 0.f;
    for (int s2 = 0; s2 < S_; ++s2) { const float e = expf(praw[s2] - m); pL[s2] = e; sum += e; }
    const float invs = 1.0f / sum;
    for (int s2 = 0; s2 < S_; ++s2) pL[s2] *= invs;
    for (int s2 = 0; s2 < S_; ++s2)
      for (int k = 0; k < K_; ++k) qL[s2 * K_ + k] = pL[s2] * cfL[k];
  }
  __syncthreads();

  // ---- filt -> LDS; leader window gather (both depend on step above)
  for (int o = tid; o < OUT_; o += 256) {
    float acc = 0.f;
#pragma unroll
    for (int s2 = 0; s2 < S_; ++s2) {
      acc += pL[s2] * mhb[s2 * OUT_ + o];
#pragma unroll
      for (int k = 0; k < K_; ++k)
        acc += qL[s2 * K_ + k] * mhw[(size_t)s2 * (K_ * OUT_) + k * OUT_ + o];
    }
    flL[o] = acc;
  }
  for (int i = tid; i < K_ * H_; i += 256) {
    const int k = i / H_, h = i - k * H_;
    ssL[k][h] = seq[((size_t)(b * C_ + leadL[k])) * SEQLEN + (L_ + h - ltL[k])] * srL[k];
  }
  __syncthreads();

  // ---- 96-pt rfft (DFT) of ss rows and yn
  for (int u = tid; u < K_ * F2_ + F2_; u += 256) {
    if (u < K_ * F2_) {
      const int k = u / F2_, f = u - k * F2_;
      float re = 0.f, im = 0.f; int m = 0;
      for (int h = 0; h < H_; ++h) {
        const float v = ssL[k][h];
        re = fmaf(v, cosT[m], re); im = fmaf(-v, sinT[m], im);
        m += f; if (m >= 96) m -= 96;
      }
      sfr[k][f] = re; sfi[k][f] = im;
    } else {
      const int f = u - K_ * F2_;
      float re = 0.f, im = 0.f; int m = 0;
      for (int h = 0; h < H_; ++h) {
        const float v = ynL[h];
        re = fmaf(v, cosT[m], re); im = fmaf(-v, sinT[m], im);
        m += f; if (m >= 96) m -= 96;
      }
      yfr[f] = re; yfi[f] = im;
    }
  }
  __syncthreads();

  if (tid < F2_) {
    const int f = tid;
    float s1r = 0.f, s1i = 0.f, s2r = 0.f, s2i = 0.f;
    const float yr = yfr[f], yi = yfi[f];
#pragma unroll
    for (int k = 0; k < K_; ++k) {
      const float fa = flL[k * F2_ + f], fb = flL[(K_ + k) * F2_ + f];
      const float ar = sfr[k][f] * fa, ai = sfi[k][f] * fa;
      s1r += ar; s1i += ai;
      s2r += (ar - yr) * fb; s2i += (ai - yi) * fb;
    }
    const float fc = flL[2 * K_ * F2_ + f];
    catr[f] = s1r;            cati[f] = s1i;
    catr[F2_ + f] = s2r;      cati[F2_ + f] = s2i;
    catr[2 * F2_ + f] = yr * fc; cati[2 * F2_ + f] = yi * fc;
  }
  __syncthreads();

  if (tid < F2_) {
    const int o = tid;
    float ar = mbr[o], ai = mbi[o];
    const float* wr = mwr + (size_t)o * (3 * F2_);
    const float* wi = mwi + (size_t)o * (3 * F2_);
    for (int f = 0; f < 3 * F2_; ++f) {
      const float cr = catr[f], ci = cati[f];
      const float wrr = wr[f], wii = wi[f];
      ar += cr * wrr - ci * wii;
      ai += cr * wii + ci * wrr;
    }
    ofr[o] = ar; ofi[o] = ai;
  }
  __syncthreads();

  if (tid < H_) {
    const int h = tid;
    float val = ofr[0] + ofr[48] * ((h & 1) ? -1.f : 1.f);
    int m = h;                                  // (f*h)%96 for f=1
    for (int f = 1; f < 48; ++f) {
      val += 2.f * (ofr[f] * cosT[m] - ofi[f] * sinT[m]);
      m += h; if (m >= 96) m -= 96;
    }
    val *= (1.0f / 96.0f);
    const float mu = mu_g[bc], stdv = std_g[bc];
    out[((size_t)b * H_ + h) * C_ + c] = (ynL[h] + val) * stdv + mu;
  }
}

// ---------------------------------------------------------------- launch
extern "C" void kernel_launch(void* const* d_in, const int* in_sizes, int n_in,
                              void* d_out, int out_size, void* d_ws, size_t ws_size,
                              hipStream_t stream) {
  const float* x    = (const float*)d_in[0];
  const float* yh   = (const float*)d_in[1];
  const float* temp = (const float*)d_in[2];
  const float* clsw = (const float*)d_in[3];
  const float* bst  = (const float*)d_in[4];
  const float* sbias= (const float*)d_in[5];
  const float* mhw  = (const float*)d_in[6];
  const float* mhb  = (const float*)d_in[7];
  const float* mwr  = (const float*)d_in[8];
  const float* mwi  = (const float*)d_in[9];
  const float* mbr  = (const float*)d_in[10];
  const float* mbi  = (const float*)d_in[11];
  float* out = (float*)d_out;

  float* ws = (float*)d_ws;
  float* seq    = ws;                                   // 2048*816
  float* mu_g   = seq + (size_t)2048 * SEQLEN;          // 2048
  float* std_g  = mu_g + 2048;                          // 2048
  float* r_arr  = std_g + 2048;                         // 262144
  int*   t_arr  = (int*)(r_arr + (size_t)2048 * C_);    // 262144
  float2* Rc    = (float2*)(t_arr + (size_t)2048 * C_); // 2048*361 float2
  float2* wtab  = Rc + (size_t)2048 * NF;               // 720 float2

  hipLaunchKernelGGL(k0_tab, dim3(1), dim3(256), 0, stream, wtab);
  hipLaunchKernelGGL(k1_fused, dim3(B_ * C_ / 2), dim3(256), 0, stream, x, yh, wtab, seq, mu_g, std_g, Rc);
  hipLaunchKernelGGL(k2_fft, dim3(B_ * 576), dim3(256), 0, stream, Rc, wtab, r_arr, t_arr);
  hipLaunchKernelGGL(k34_fused, dim3(B_ * C_), dim3(256), 0, stream,
                     x, temp, clsw, bst, sbias, mhw, mhb, r_arr, t_arr,
                     seq, mu_g, std_g, mwr, mwi, mbr, mbi, out);
}

// Round 12
// 897.645 us; speedup vs baseline: 1.0560x; 1.0560x over previous
//
#include <hip/hip_runtime.h>
#include <math.h>

#define B_ 16
#define L_ 720
#define C_ 128
#define H_ 96
#define F2_ 49
#define K_ 8
#define S_ 8
#define OUT_ 833          // F2*(2K+1)
#define SEQLEN 816        // L + H
#define NF 361            // rfft bins for L=720

__device__ __forceinline__ float2 cmulp(float2 a, float2 w) {   // a * w (complex)
  return make_float2(a.x*w.x - a.y*w.y, a.x*w.y + a.y*w.x);
}

// Per-wave LDS fence: all my LDS ops done, and no compiler reordering across it (rule #18).
#define WSYNC() do { asm volatile("s_waitcnt lgkmcnt(0)" ::: "memory"); __builtin_amdgcn_sched_barrier(0); } while (0)

// W5^m = e^{+2*pi*i*m/5}
__device__ __constant__ float W5X[5] = {1.f, 0.30901699437494742f, -0.80901699437494745f, -0.80901699437494745f, 0.30901699437494742f};
__device__ __constant__ float W5Y[5] = {0.f, 0.95105651629515357f, 0.58778525229247312f, -0.58778525229247312f, -0.95105651629515357f};

// DFT-8, positive exponent (omega = e^{+i*pi/4}) — verified in R9.
__device__ __forceinline__ void dft8_pos(const float2 zin[8], float2 X[8]) {
  const float RH = 0.70710678118654752440f;
  const float2 A0 = make_float2(zin[0].x+zin[4].x, zin[0].y+zin[4].y);
  const float2 A1 = make_float2(zin[0].x-zin[4].x, zin[0].y-zin[4].y);
  const float2 A2 = make_float2(zin[2].x+zin[6].x, zin[2].y+zin[6].y);
  const float2 A3 = make_float2(zin[2].x-zin[6].x, zin[2].y-zin[6].y);
  const float2 A4 = make_float2(zin[1].x+zin[5].x, zin[1].y+zin[5].y);
  const float2 A5 = make_float2(zin[1].x-zin[5].x, zin[1].y-zin[5].y);
  const float2 A6 = make_float2(zin[3].x+zin[7].x, zin[3].y+zin[7].y);
  const float2 A7 = make_float2(zin[3].x-zin[7].x, zin[3].y-zin[7].y);
  const float2 B0 = make_float2(A0.x+A2.x, A0.y+A2.y);
  const float2 B1 = make_float2(A0.x-A2.x, A0.y-A2.y);
  const float2 B2 = make_float2(A4.x+A6.x, A4.y+A6.y);
  const float2 B3 = make_float2(A4.x-A6.x, A4.y-A6.y);
  X[0] = make_float2(B0.x+B2.x, B0.y+B2.y);
  X[4] = make_float2(B0.x-B2.x, B0.y-B2.y);
  X[2] = make_float2(B1.x - B3.y, B1.y + B3.x);   // B1 + i*B3
  X[6] = make_float2(B1.x + B3.y, B1.y - B3.x);   // B1 - i*B3
  const float2 CI   = make_float2(-A3.y, A3.x);   // i*A3
  const float2 W1s1 = make_float2((A5.x - A5.y)*RH, (A5.x + A5.y)*RH);   // w^1*A5
  const float2 W3s1 = make_float2((-A5.x - A5.y)*RH, (A5.x - A5.y)*RH);  // w^3*A5
  const float2 W1s3 = make_float2((A7.x - A7.y)*RH, (A7.x + A7.y)*RH);   // w^1*A7
  const float2 W3s3 = make_float2((-A7.x - A7.y)*RH, (A7.x - A7.y)*RH);  // w^3*A7
  X[1] = make_float2(A1.x + CI.x + W1s1.x + W3s3.x, A1.y + CI.y + W1s1.y + W3s3.y);
  X[5] = make_float2(A1.x + CI.x - W1s1.x - W3s3.x, A1.y + CI.y - W1s1.y - W3s3.y);
  X[3] = make_float2(A1.x - CI.x + W3s1.x + W1s3.x, A1.y - CI.y + W3s1.y + W1s3.y);
  X[7] = make_float2(A1.x - CI.x - W3s1.x - W1s3.x, A1.y - CI.y - W3s1.y - W1s3.y);
}

// ---------------------------------------------------------------- K0: twiddle table (once per launch)
__global__ __launch_bounds__(256) void k0_tab(float2* __restrict__ wtab_g) {
  for (int k = threadIdx.x; k < L_; k += 256) {
    double ang = (double)k * 0.008726646259971647884;   // 2*pi/720
    wtab_g[k] = make_float2((float)cos(ang), (float)sin(ang));
  }
}

// ---------------------------------------------------------------- K1: normalize + forward rfft, 2 adjacent channels per block
__global__ __launch_bounds__(256) void k1_fused(const float* __restrict__ x,
                                                const float* __restrict__ yh,
                                                const float2* __restrict__ wtab_g,
                                                float* __restrict__ seq,
                                                float* __restrict__ mu_g,
                                                float* __restrict__ std_g,
                                                float2* __restrict__ Rc) {
  const int bc0 = blockIdx.x * 2;       // channels bc0, bc0+1 (adjacent c -> float2 loads)
  const int b = bc0 >> 7, c0 = bc0 & 127;
  const int tid = threadIdx.x;
  __shared__ float xrow[2][L_];
  __shared__ float yrow[2][H_];
  __shared__ float2 wt[L_];
  __shared__ float red[4];

  const float* xb = x + (size_t)b * L_ * C_ + c0;
  for (int l = tid; l < L_; l += 256) {
    const float2 v = *(const float2*)&xb[(size_t)l * C_];
    xrow[0][l] = v.x; xrow[1][l] = v.y;
  }
  const float* yb = yh + (size_t)b * H_ * C_ + c0;
  if (tid < H_) {
    const float2 v = *(const float2*)&yb[(size_t)tid * C_];
    yrow[0][tid] = v.x; yrow[1][tid] = v.y;
  }
  for (int k = tid; k < L_; k += 256) wt[k] = wtab_g[k];
  __syncthreads();

  for (int ch = 0; ch < 2; ++ch) {
    float s = 0.f;
    for (int l = tid; l < L_; l += 256) s += xrow[ch][l];
    for (int off = 32; off; off >>= 1) s += __shfl_down(s, off, 64);
    if ((tid & 63) == 0) red[tid >> 6] = s;
    __syncthreads();
    const float mu = (red[0] + red[1] + red[2] + red[3]) * (1.0f / L_);
    __syncthreads();
    float vs = 0.f;
    for (int l = tid; l < L_; l += 256) { float d = xrow[ch][l] - mu; vs += d * d; }
    for (int off = 32; off; off >>= 1) vs += __shfl_down(vs, off, 64);
    if ((tid & 63) == 0) red[tid >> 6] = vs;
    __syncthreads();
    const float stdv = sqrtf((red[0] + red[1] + red[2] + red[3]) * (1.0f / L_) + 1e-8f);
    const float inv = 1.0f / stdv;
    if (tid == 0) { mu_g[bc0 + ch] = mu; std_g[bc0 + ch] = stdv; }
    __syncthreads();                     // red reused next ch; also xrow rewrite guard
    float* sq = seq + (size_t)(bc0 + ch) * SEQLEN;
    for (int l = tid; l < L_; l += 256) { const float v = (xrow[ch][l] - mu) * inv; xrow[ch][l] = v; sq[l] = v; }
    if (tid < H_) sq[L_ + tid] = (yrow[ch][tid] - mu) * inv;
    __syncthreads();
  }

  for (int u = tid; u < 2 * NF; u += 256) {   // rfft (negative exponent), from normalized LDS rows
    const int row = u / NF, f = u - row * NF;
    float re = 0.f, im = 0.f;
    int m = 0;
    const float* xr = xrow[row];
    for (int l = 0; l < L_; ++l) {
      const float v = xr[l];
      const float2 w = wt[m];
      re = fmaf(v, w.x, re);
      im = fmaf(-v, w.y, im);
      m += f; if (m >= L_) m -= L_;
    }
    Rc[(size_t)(bc0 + row) * NF + f] = make_float2(re, im);
  }
}

// ---------------------------------------------------------------- K2: per-wave spectral product + real-packed 360-pt IFFT, 2 pairs/wave/iter
// cc (real, len 720) via z[n] = cc[2n] + i*cc[2n+1] = IDFT360(Z); Z from Hermitian P (see R9).
// Stage-1 = 90 tasks (pair, K2) over 64 lanes in 2 FENCED passes: R11's unroll interleaved both
// passes' chains -> 124 MB scratch spill; sched_barrier(0) between passes keeps one chain live.
// NOTE: __launch_bounds__(256,2) is load-bearing (R4/R6: tighter bounds force scratch spills).
__global__ __launch_bounds__(256, 2) void k2_fft(const float2* __restrict__ Rc,
                                                 const float2* __restrict__ wtab_g,
                                                 float* __restrict__ r_arr,
                                                 int* __restrict__ t_arr) {
  // XCD-aware bijective swizzle (T1): grid = 9216 = 8 * 1152 -> each XCD gets 2 contiguous batches.
  const int phys = blockIdx.x;
  int idx = (phys & 7) * 1152 + (phys >> 3);
  const int b = idx / 576;
  idx -= b * 576;
  int g = 0;
  while (true) { const int cnt = (8 - g) << 4; if (idx < cnt) break; idx -= cnt; ++g; }
  const int rows = 8 - g;
  const int c1 = (g << 4) + idx / rows;
  const int c2t = g + idx % rows;
  const int c2base = c2t << 4;
  const int tid = threadIdx.x;
  const int wid = tid >> 6, lane = tid & 63;

  __shared__ float2 r1c[NF];
  __shared__ float2 t9[81];                      // W9^{a*c} at [9a+c]
  __shared__ float2 t45[45];                     // W45^{b*c} at [9b+c]
  __shared__ float2 Yw[4][2][360];               // per-wave, per-pair stage-1 out [n1*45+K2]
  __shared__ __align__(16) float ccw[4][2][728]; // per-wave, per-pair cc row

  for (int f = tid; f < NF; f += 256) r1c[f] = Rc[((size_t)(b * C_ + c1)) * NF + f];
  for (int i = tid; i < 81; i += 256) { int a = i / 9, c = i % 9; t9[i] = wtab_g[80 * ((a * c) % 9)]; }
  for (int i = tid; i < 45; i += 256) { int bb = i / 9, c = i % 9; t45[i] = wtab_g[16 * bb * c]; }
  __syncthreads();                   // the only block-wide barrier

  const float SCALE = 1.0f / 518400.0f;   // 1/720^2

  for (int it = 0; it < 2; ++it) {
    const int c2A = c2base + (wid << 2) + 2 * it;    // pair A; pair B = c2A+1
    if (c2A + 1 < c1) continue;      // both pairs below diagonal: nothing would be emitted
    const float2* R2A = Rc + ((size_t)(b * C_ + c2A)) * NF;   // L2-hot after swizzle
    const float2* R2B = R2A + NF;

    // ---- stage 1: 90 tasks (pair, K2); Z on the fly + DFT-8 + exact W360 twiddle.
    {
      auto stage1_task = [&](int t) {
        const int pr = (t >= 45) ? 1 : 0;
        const int K2 = t - 45 * pr;
        const float2* R2 = pr ? R2B : R2A;
        float2 zin[8];
#pragma unroll
        for (int q1 = 0; q1 < 8; ++q1) {
          const int k = 45 * q1 + K2;              // in [0, 360)
          const int fB = 360 - k;                  // in [1, 360]
          const float2 a1 = r1c[k];
          const float2 a2 = r1c[fB];
          const float2 w  = wtab_g[k];
          const float2 b1 = R2[k];
          const float2 b2 = R2[fB];
          const float2 pA = make_float2(a1.x*b1.x + a1.y*b1.y, a1.y*b1.x - a1.x*b1.y);
          float2 pB = make_float2(a2.x*b2.x + a2.y*b2.y, a2.y*b2.x - a2.x*b2.y);
          pB.y = (k == 0) ? pB.y : -pB.y;          // conj for k>=1
          const float2 E = make_float2(pA.x + pB.x, pA.y + pB.y);
          const float2 O = make_float2(pA.x - pB.x, pA.y - pB.y);
          const float2 Ow = cmulp(O, w);
          zin[q1] = make_float2(E.x - Ow.y, E.y + Ow.x);   // E + i*Ow
        }
        float2 X[8];
        dft8_pos(zin, X);
        int m = 0;                                 // m = 2*K2*n1 <= 616: no mod needed
#pragma unroll
        for (int n1 = 0; n1 < 8; ++n1) {
          Yw[wid][pr][n1 * 45 + K2] = cmulp(X[n1], wtab_g[m]);   // exact W360^{K2*n1}
          m += 2 * K2;
        }
      };
      stage1_task(lane);                         // pass 0: t = lane (all 64 lanes, t < 90)
      __builtin_amdgcn_sched_barrier(0);         // hard fence: do NOT interleave pass chains (R11 spill)
      if (lane < 26) stage1_task(lane + 64);     // pass 1: t = 64..89
    }
    WSYNC();   // my wave's Yw writes visible to my wave's stage-2 reads

    // ---- stage 2: DFT-45 per n1-row (9x5 CT), complex out, both pairs with shared reg tables.
    {
      const int n1 = lane >> 3;
      const int cq = lane & 7;
      const int nci = (cq == 0) ? 2 : 1;
      int cvals[2] = { cq, 8 };

      float2 T9r[2][9], T45r[2][5];
#pragma unroll
      for (int ci = 0; ci < 2; ++ci) if (ci < nci) {
        const int c = cvals[ci];
#pragma unroll
        for (int a = 0; a < 9; ++a) T9r[ci][a] = t9[9 * a + c];
#pragma unroll
        for (int bq = 0; bq < 5; ++bq) T45r[ci][bq] = t45[9 * bq + c];
      }

#pragma unroll
      for (int pp = 0; pp < 2; ++pp) {
        const float2* Yrow = &Yw[wid][pp][n1 * 45];
        float yr[2][5], yi[2][5];
#pragma unroll
        for (int ci = 0; ci < 2; ++ci)
#pragma unroll
          for (int d = 0; d < 5; ++d) { yr[ci][d] = 0.f; yi[ci][d] = 0.f; }

#pragma unroll
        for (int bq = 0; bq < 5; ++bq) {
          float2 z[9];
#pragma unroll
          for (int a = 0; a < 9; ++a) z[a] = Yrow[5 * a + bq];
#pragma unroll
          for (int ci = 0; ci < 2; ++ci) if (ci < nci) {
            float ur = 0.f, ui = 0.f;
#pragma unroll
            for (int a = 0; a < 9; ++a) {
              ur += z[a].x * T9r[ci][a].x - z[a].y * T9r[ci][a].y;
              ui += z[a].x * T9r[ci][a].y + z[a].y * T9r[ci][a].x;
            }
            const float2 tw = T45r[ci][bq];
            const float vr = ur * tw.x - ui * tw.y;
            const float vi = ur * tw.y + ui * tw.x;
#pragma unroll
            for (int d = 0; d < 5; ++d) {
              const int m = (bq * d) % 5;                   // compile-time
              yr[ci][d] += vr * W5X[m] - vi * W5Y[m];
              yi[ci][d] += vr * W5Y[m] + vi * W5X[m];
            }
          }
        }
        float2* cc2 = (float2*)(&ccw[wid][pp][0]);
#pragma unroll
        for (int ci = 0; ci < 2; ++ci) if (ci < nci) {
          const int c = cvals[ci];
#pragma unroll
          for (int d = 0; d < 5; ++d) {
            const int n2 = c + 9 * d;
            cc2[n1 + 8 * n2] = make_float2(yr[ci][d], yi[ci][d]);   // cc[2n], cc[2n+1]
          }
        }
      }
    }
    WSYNC();   // ccw writes visible to my wave's scans

    // ---- merged peak scans, half-wave per row (lanes 0-31: pair A, 32-63: pair B).
    {
      const int half = lane >> 5, sl = lane & 31;
      const int c2h = c2A + half;
      const float* cr = ccw[wid][half];
      float bvF = 0.f; int btF = 1;
      float bvM = 0.f; int uM  = 719;      // -> t' = 1 on all-zero
      for (int i = sl; i < 719; i += 32) {
        const int u = i + 1;               // 1..719
        const float v  = fabsf(cr[u]);
        const float lf = fabsf(cr[u - 1]);
        const float rt = fabsf(cr[(u == 719) ? 0 : (u + 1)]);
        if (v >= lf && v >= rt) {
          if (u <= 718 && (v > bvF || (v == bvF && u < btF))) { bvF = v; btF = u; }
          if (u >= 2   && (v > bvM || (v == bvM && u > uM)))  { bvM = v; uM  = u; }
        }
      }
      for (int off = 16; off; off >>= 1) {
        const float ovF = __shfl_down(bvF, off, 32); const int otF = __shfl_down(btF, off, 32);
        if (ovF > bvF || (ovF == bvF && otF < btF)) { bvF = ovF; btF = otF; }
        const float ovM = __shfl_down(bvM, off, 32); const int ouM = __shfl_down(uM, off, 32);
        if (ovM > bvM || (ovM == bvM && ouM > uM)) { bvM = ovM; uM = ouM; }
      }
      if (sl == 0 && c2h >= c1) {
        const float rF = (bvF > 0.f) ? cr[btF] * SCALE : 0.f;
        const size_t o = ((size_t)(b * C_ + c1)) * C_ + c2h;
        r_arr[o] = rF; t_arr[o] = btF;
        if (c2h > c1) {
          const float rM = (bvM > 0.f) ? cr[uM] * SCALE : 0.f;
          const size_t o2 = ((size_t)(b * C_ + c2h)) * C_ + c1;
          r_arr[o2] = rM; t_arr[o2] = 720 - uM;
        }
      }
    }
    WSYNC();   // scans' ccw reads done before next it overwrites
  }
}

// ---------------------------------------------------------------- K34: leaders/softmax/filt + spectral mix + output (fused; filt/leads stay in LDS)
__global__ __launch_bounds__(256) void k34_fused(const float* __restrict__ x,
                                                 const float* __restrict__ temperature,
                                                 const float* __restrict__ cls_w,
                                                 const float* __restrict__ basic_state,
                                                 const float* __restrict__ state_bias,
                                                 const float* __restrict__ mhw,
                                                 const float* __restrict__ mhb,
                                                 const float* __restrict__ r_arr,
                                                 const int* __restrict__ t_arr,
                                                 const float* __restrict__ seq,
                                                 const float* __restrict__ mu_g,
                                                 const float* __restrict__ std_g,
                                                 const float* __restrict__ mwr,
                                                 const float* __restrict__ mwi,
                                                 const float* __restrict__ mbr,
                                                 const float* __restrict__ mbi,
                                                 float* __restrict__ out) {
  const int bc = blockIdx.x;
  const int b = bc >> 7, c = bc & 127;
  const int tid = threadIdx.x;
  __shared__ float caL[C_], rL[C_];
  __shared__ int tL[C_];
  __shared__ float xrowL[L_];
  __shared__ float cfL[K_], srL[K_], pL[S_], qL[S_ * K_], praw[S_];
  __shared__ int leadL[K_], ltL[K_];
  __shared__ float cosT[96], sinT[96];
  __shared__ float ssL[K_][H_], ynL[H_], flL[OUT_];
  __shared__ float sfr[K_][F2_], sfi[K_][F2_], yfr[F2_], yfi[F2_];
  __shared__ float catr[3 * F2_], cati[3 * F2_], ofr[F2_], ofi[F2_];

  // ---- gather inputs (k3 part + k4 tables)
  const float* xb = x + (size_t)b * L_ * C_ + c;
  for (int l = tid; l < L_; l += 256) xrowL[l] = xb[(size_t)l * C_];
  if (tid < C_) {
    const float r = r_arr[(size_t)bc * C_ + tid];
    rL[tid] = r; caL[tid] = fabsf(r);
    tL[tid] = t_arr[(size_t)bc * C_ + tid];
  }
  if (tid >= 128 && tid < 224) {
    const int h = tid - 128;
    const float ang = (float)h * (float)(6.283185307179586 / 96.0);
    cosT[h] = cosf(ang); sinT[h] = sinf(ang);
    ynL[h] = seq[(size_t)bc * SEQLEN + L_ + h];
  }
  __syncthreads();

  // ---- top-k leaders + corr softmax (serial, tiny)
  if (tid == 0) {
    const float T = temperature[0];
    float lg[K_ + 1];
    lg[0] = 1.0f / T;
    for (int k = 0; k < K_; ++k) {       // stable top-k: strict > keeps smallest index on ties
      float bvv = -1.f; int bi = 0;
      for (int jj = 0; jj < C_; ++jj) { const float v = caL[jj]; if (v > bvv) { bvv = v; bi = jj; } }
      leadL[k] = bi; ltL[k] = tL[bi];
      const float rv = rL[bi];
      srL[k] = (rv > 0.f) ? 1.f : ((rv < 0.f) ? -1.f : 0.f);
      lg[k + 1] = bvv / T;
      caL[bi] = -2.f;
    }
    float m = lg[0];
    for (int k = 1; k <= K_; ++k) m = fmaxf(m, lg[k]);
    float sum = 0.f, e[K_ + 1];
    for (int k = 0; k <= K_; ++k) { e[k] = expf(lg[k] - m); sum += e[k]; }
    const float invs = 1.0f / sum;
    for (int k = 0; k < K_; ++k) cfL[k] = e[k + 1] * invs;
  }

  // ---- p logits: 8 groups of 32 lanes
  {
    const int gg = tid >> 5, lane = tid & 31;
    float acc = 0.f;
    const float* w = cls_w + (size_t)gg * L_;
    for (int l = lane; l < L_; l += 32) acc += xrowL[l] * w[l];
    for (int off = 16; off; off >>= 1) acc += __shfl_down(acc, off, 32);
    if (lane == 0) praw[gg] = acc + state_bias[gg] + basic_state[c * S_ + gg];
  }
  __syncthreads();
  if (tid == 0) {
    float m = praw[0];
    for (int s2 = 1; s2 < S_; ++s2) m = fmaxf(m, praw[s2]);
    float sum = 0.f;
    for (int s2 = 0; s2 < S_; ++s2) { const float e = expf(praw[s2] - m); pL[s2] = e; sum += e; }
    const float invs = 1.0f / sum;
    for (int s2 = 0; s2 < S_; ++s2) pL[s2] *= invs;
    for (int s2 = 0; s2 < S_; ++s2)
      for (int k = 0; k < K_; ++k) qL[s2 * K_ + k] = pL[s2] * cfL[k];
  }
  __syncthreads();

  // ---- filt -> LDS; leader window gather (both depend on step above)
  for (int o = tid; o < OUT_; o += 256) {
    float acc = 0.f;
#pragma unroll
    for (int s2 = 0; s2 < S_; ++s2) {
      acc += pL[s2] * mhb[s2 * OUT_ + o];
#pragma unroll
      for (int k = 0; k < K_; ++k)
        acc += qL[s2 * K_ + k] * mhw[(size_t)s2 * (K_ * OUT_) + k * OUT_ + o];
    }
    flL[o] = acc;
  }
  for (int i = tid; i < K_ * H_; i += 256) {
    const int k = i / H_, h = i - k * H_;
    ssL[k][h] = seq[((size_t)(b * C_ + leadL[k])) * SEQLEN + (L_ + h - ltL[k])] * srL[k];
  }
  __syncthreads();

  // ---- 96-pt rfft (DFT) of ss rows and yn
  for (int u = tid; u < K_ * F2_ + F2_; u += 256) {
    if (u < K_ * F2_) {
      const int k = u / F2_, f = u - k * F2_;
      float re = 0.f, im = 0.f; int m = 0;
      for (int h = 0; h < H_; ++h) {
        const float v = ssL[k][h];
        re = fmaf(v, cosT[m], re); im = fmaf(-v, sinT[m], im);
        m += f; if (m >= 96) m -= 96;
      }
      sfr[k][f] = re; sfi[k][f] = im;
    } else {
      const int f = u - K_ * F2_;
      float re = 0.f, im = 0.f; int m = 0;
      for (int h = 0; h < H_; ++h) {
        const float v = ynL[h];
        re = fmaf(v, cosT[m], re); im = fmaf(-v, sinT[m], im);
        m += f; if (m >= 96) m -= 96;
      }
      yfr[f] = re; yfi[f] = im;
    }
  }
  __syncthreads();

  if (tid < F2_) {
    const int f = tid;
    float s1r = 0.f, s1i = 0.f, s2r = 0.f, s2i = 0.f;
    const float yr = yfr[f], yi = yfi[f];
#pragma unroll
    for (int k = 0; k < K_; ++k) {
      const float fa = flL[k * F2_ + f], fb = flL[(K_ + k) * F2_ + f];
      const float ar = sfr[k][f] * fa, ai = sfi[k][f] * fa;
      s1r += ar; s1i += ai;
      s2r += (ar - yr) * fb; s2i += (ai - yi) * fb;
    }
    const float fc = flL[2 * K_ * F2_ + f];
    catr[f] = s1r;            cati[f] = s1i;
    catr[F2_ + f] = s2r;      cati[F2_ + f] = s2i;
    catr[2 * F2_ + f] = yr * fc; cati[2 * F2_ + f] = yi * fc;
  }
  __syncthreads();

  if (tid < F2_) {
    const int o = tid;
    float ar = mbr[o], ai = mbi[o];
    const float* wr = mwr + (size_t)o * (3 * F2_);
    const float* wi = mwi + (size_t)o * (3 * F2_);
    for (int f = 0; f < 3 * F2_; ++f) {
      const float cr = catr[f], ci = cati[f];
      const float wrr = wr[f], wii = wi[f];
      ar += cr * wrr - ci * wii;
      ai += cr * wii + ci * wrr;
    }
    ofr[o] = ar; ofi[o] = ai;
  }
  __syncthreads();

  if (tid < H_) {
    const int h = tid;
    float val = ofr[0] + ofr[48] * ((h & 1) ? -1.f : 1.f);
    int m = h;                                  // (f*h)%96 for f=1
    for (int f = 1; f < 48; ++f) {
      val += 2.f * (ofr[f] * cosT[m] - ofi[f] * sinT[m]);
      m += h; if (m >= 96) m -= 96;
    }
    val *= (1.0f / 96.0f);
    const float mu = mu_g[bc], stdv = std_g[bc];
    out[((size_t)b * H_ + h) * C_ + c] = (ynL[h] + val) * stdv + mu;
  }
}

// ---------------------------------------------------------------- launch
extern "C" void kernel_launch(void* const* d_in, const int* in_sizes, int n_in,
                              void* d_out, int out_size, void* d_ws, size_t ws_size,
                              hipStream_t stream) {
  const float* x    = (const float*)d_in[0];
  const float* yh   = (const float*)d_in[1];
  const float* temp = (const float*)d_in[2];
  const float* clsw = (const float*)d_in[3];
  const float* bst  = (const float*)d_in[4];
  const float* sbias= (const float*)d_in[5];
  const float* mhw  = (const float*)d_in[6];
  const float* mhb  = (const float*)d_in[7];
  const float* mwr  = (const float*)d_in[8];
  const float* mwi  = (const float*)d_in[9];
  const float* mbr  = (const float*)d_in[10];
  const float* mbi  = (const float*)d_in[11];
  float* out = (float*)d_out;

  float* ws = (float*)d_ws;
  float* seq    = ws;                                   // 2048*816
  float* mu_g   = seq + (size_t)2048 * SEQLEN;          // 2048
  float* std_g  = mu_g + 2048;                          // 2048
  float* r_arr  = std_g + 2048;                         // 262144
  int*   t_arr  = (int*)(r_arr + (size_t)2048 * C_);    // 262144
  float2* Rc    = (float2*)(t_arr + (size_t)2048 * C_); // 2048*361 float2
  float2* wtab  = Rc + (size_t)2048 * NF;               // 720 float2

  hipLaunchKernelGGL(k0_tab, dim3(1), dim3(256), 0, stream, wtab);
  hipLaunchKernelGGL(k1_fused, dim3(B_ * C_ / 2), dim3(256), 0, stream, x, yh, wtab, seq, mu_g, std_g, Rc);
  hipLaunchKernelGGL(k2_fft, dim3(B_ * 576), dim3(256), 0, stream, Rc, wtab, r_arr, t_arr);
  hipLaunchKernelGGL(k34_fused, dim3(B_ * C_), dim3(256), 0, stream,
                     x, temp, clsw, bst, sbias, mhw, mhb, r_arr, t_arr,
                     seq, mu_g, std_g, mwr, mwi, mbr, mbi, out);
}

// Round 13
// 858.015 us; speedup vs baseline: 1.1047x; 1.0462x over previous
//
#include <hip/hip_runtime.h>
#include <math.h>

#define B_ 16
#define L_ 720
#define C_ 128
#define H_ 96
#define F2_ 49
#define K_ 8
#define S_ 8
#define OUT_ 833          // F2*(2K+1)
#define SEQLEN 816        // L + H
#define NF 361            // rfft bins for L=720

__device__ __forceinline__ float2 cmulp(float2 a, float2 w) {   // a * w (complex)
  return make_float2(a.x*w.x - a.y*w.y, a.x*w.y + a.y*w.x);
}

// Per-wave LDS fence: all my LDS ops done, and no compiler reordering across it (rule #18).
#define WSYNC() do { asm volatile("s_waitcnt lgkmcnt(0)" ::: "memory"); __builtin_amdgcn_sched_barrier(0); } while (0)

// W5^m = e^{+2*pi*i*m/5}
__device__ __constant__ float W5X[5] = {1.f, 0.30901699437494742f, -0.80901699437494745f, -0.80901699437494745f, 0.30901699437494742f};
__device__ __constant__ float W5Y[5] = {0.f, 0.95105651629515357f, 0.58778525229247312f, -0.58778525229247312f, -0.95105651629515357f};

// DFT-8, positive exponent (omega = e^{+i*pi/4}) — verified in R9.
__device__ __forceinline__ void dft8_pos(const float2 zin[8], float2 X[8]) {
  const float RH = 0.70710678118654752440f;
  const float2 A0 = make_float2(zin[0].x+zin[4].x, zin[0].y+zin[4].y);
  const float2 A1 = make_float2(zin[0].x-zin[4].x, zin[0].y-zin[4].y);
  const float2 A2 = make_float2(zin[2].x+zin[6].x, zin[2].y+zin[6].y);
  const float2 A3 = make_float2(zin[2].x-zin[6].x, zin[2].y-zin[6].y);
  const float2 A4 = make_float2(zin[1].x+zin[5].x, zin[1].y+zin[5].y);
  const float2 A5 = make_float2(zin[1].x-zin[5].x, zin[1].y-zin[5].y);
  const float2 A6 = make_float2(zin[3].x+zin[7].x, zin[3].y+zin[7].y);
  const float2 A7 = make_float2(zin[3].x-zin[7].x, zin[3].y-zin[7].y);
  const float2 B0 = make_float2(A0.x+A2.x, A0.y+A2.y);
  const float2 B1 = make_float2(A0.x-A2.x, A0.y-A2.y);
  const float2 B2 = make_float2(A4.x+A6.x, A4.y+A6.y);
  const float2 B3 = make_float2(A4.x-A6.x, A4.y-A6.y);
  X[0] = make_float2(B0.x+B2.x, B0.y+B2.y);
  X[4] = make_float2(B0.x-B2.x, B0.y-B2.y);
  X[2] = make_float2(B1.x - B3.y, B1.y + B3.x);   // B1 + i*B3
  X[6] = make_float2(B1.x + B3.y, B1.y - B3.x);   // B1 - i*B3
  const float2 CI   = make_float2(-A3.y, A3.x);   // i*A3
  const float2 W1s1 = make_float2((A5.x - A5.y)*RH, (A5.x + A5.y)*RH);   // w^1*A5
  const float2 W3s1 = make_float2((-A5.x - A5.y)*RH, (A5.x - A5.y)*RH);  // w^3*A5
  const float2 W1s3 = make_float2((A7.x - A7.y)*RH, (A7.x + A7.y)*RH);   // w^1*A7
  const float2 W3s3 = make_float2((-A7.x - A7.y)*RH, (A7.x - A7.y)*RH);  // w^3*A7
  X[1] = make_float2(A1.x + CI.x + W1s1.x + W3s3.x, A1.y + CI.y + W1s1.y + W3s3.y);
  X[5] = make_float2(A1.x + CI.x - W1s1.x - W3s3.x, A1.y + CI.y - W1s1.y - W3s3.y);
  X[3] = make_float2(A1.x - CI.x + W3s1.x + W1s3.x, A1.y - CI.y + W3s1.y + W1s3.y);
  X[7] = make_float2(A1.x - CI.x - W3s1.x - W1s3.x, A1.y - CI.y - W3s1.y - W1s3.y);
}

// ---------------------------------------------------------------- K0: twiddle table (once per launch)
__global__ __launch_bounds__(256) void k0_tab(float2* __restrict__ wtab_g) {
  for (int k = threadIdx.x; k < L_; k += 256) {
    double ang = (double)k * 0.008726646259971647884;   // 2*pi/720
    wtab_g[k] = make_float2((float)cos(ang), (float)sin(ang));
  }
}

// ---------------------------------------------------------------- K1: normalize + forward rfft, 2 adjacent channels per block
__global__ __launch_bounds__(256) void k1_fused(const float* __restrict__ x,
                                                const float* __restrict__ yh,
                                                const float2* __restrict__ wtab_g,
                                                float* __restrict__ seq,
                                                float* __restrict__ mu_g,
                                                float* __restrict__ std_g,
                                                float2* __restrict__ Rc) {
  const int bc0 = blockIdx.x * 2;       // channels bc0, bc0+1 (adjacent c -> float2 loads)
  const int b = bc0 >> 7, c0 = bc0 & 127;
  const int tid = threadIdx.x;
  __shared__ float xrow[2][L_];
  __shared__ float yrow[2][H_];
  __shared__ float2 wt[L_];
  __shared__ float red[4];

  const float* xb = x + (size_t)b * L_ * C_ + c0;
  for (int l = tid; l < L_; l += 256) {
    const float2 v = *(const float2*)&xb[(size_t)l * C_];
    xrow[0][l] = v.x; xrow[1][l] = v.y;
  }
  const float* yb = yh + (size_t)b * H_ * C_ + c0;
  if (tid < H_) {
    const float2 v = *(const float2*)&yb[(size_t)tid * C_];
    yrow[0][tid] = v.x; yrow[1][tid] = v.y;
  }
  for (int k = tid; k < L_; k += 256) wt[k] = wtab_g[k];
  __syncthreads();

  for (int ch = 0; ch < 2; ++ch) {
    float s = 0.f;
    for (int l = tid; l < L_; l += 256) s += xrow[ch][l];
    for (int off = 32; off; off >>= 1) s += __shfl_down(s, off, 64);
    if ((tid & 63) == 0) red[tid >> 6] = s;
    __syncthreads();
    const float mu = (red[0] + red[1] + red[2] + red[3]) * (1.0f / L_);
    __syncthreads();
    float vs = 0.f;
    for (int l = tid; l < L_; l += 256) { float d = xrow[ch][l] - mu; vs += d * d; }
    for (int off = 32; off; off >>= 1) vs += __shfl_down(vs, off, 64);
    if ((tid & 63) == 0) red[tid >> 6] = vs;
    __syncthreads();
    const float stdv = sqrtf((red[0] + red[1] + red[2] + red[3]) * (1.0f / L_) + 1e-8f);
    const float inv = 1.0f / stdv;
    if (tid == 0) { mu_g[bc0 + ch] = mu; std_g[bc0 + ch] = stdv; }
    __syncthreads();                     // red reused next ch; also xrow rewrite guard
    float* sq = seq + (size_t)(bc0 + ch) * SEQLEN;
    for (int l = tid; l < L_; l += 256) { const float v = (xrow[ch][l] - mu) * inv; xrow[ch][l] = v; sq[l] = v; }
    if (tid < H_) sq[L_ + tid] = (yrow[ch][tid] - mu) * inv;
    __syncthreads();
  }

  for (int u = tid; u < 2 * NF; u += 256) {   // rfft (negative exponent), from normalized LDS rows
    const int row = u / NF, f = u - row * NF;
    float re = 0.f, im = 0.f;
    int m = 0;
    const float* xr = xrow[row];
    for (int l = 0; l < L_; ++l) {
      const float v = xr[l];
      const float2 w = wt[m];
      re = fmaf(v, w.x, re);
      im = fmaf(-v, w.y, im);
      m += f; if (m >= L_) m -= L_;
    }
    Rc[(size_t)(bc0 + row) * NF + f] = make_float2(re, im);
  }
}

// ---------------------------------------------------------------- K2: per-wave spectral product + real-packed 360-pt IFFT, 2 pairs/wave/iter
// cc (real, len 720) via z[n] = cc[2n] + i*cc[2n+1] = IDFT360(Z); Z from Hermitian P (see R9).
// Stage-1 = R10's proven 45-lane 2-pair form. Stage-2 reads t9/t45 directly from LDS
// (broadcast-friendly) instead of 56-reg table preloads -> true VGPR need ~80.
// __launch_bounds__(256,3) caps alloc at 84: occupancy tracks VGPR (R4:84->34.5%, R10:112->20.6%).
// Spill detector: WRITE_SIZE must stay ~2 MB (R4/R6/R11 spills showed 100 MB-GB).
__global__ __launch_bounds__(256, 3) void k2_fft(const float2* __restrict__ Rc,
                                                 const float2* __restrict__ wtab_g,
                                                 float* __restrict__ r_arr,
                                                 int* __restrict__ t_arr) {
  // XCD-aware bijective swizzle (T1): grid = 9216 = 8 * 1152 -> each XCD gets 2 contiguous batches.
  const int phys = blockIdx.x;
  int idx = (phys & 7) * 1152 + (phys >> 3);
  const int b = idx / 576;
  idx -= b * 576;
  int g = 0;
  while (true) { const int cnt = (8 - g) << 4; if (idx < cnt) break; idx -= cnt; ++g; }
  const int rows = 8 - g;
  const int c1 = (g << 4) + idx / rows;
  const int c2t = g + idx % rows;
  const int c2base = c2t << 4;
  const int tid = threadIdx.x;
  const int wid = tid >> 6, lane = tid & 63;

  __shared__ float2 r1c[NF];
  __shared__ float2 t9[81];                      // W9^{a*c} at [9a+c]
  __shared__ float2 t45[45];                     // W45^{b*c} at [9b+c]
  __shared__ float2 Yw[4][2][360];               // per-wave, per-pair stage-1 out [n1*45+K2]
  __shared__ __align__(16) float ccw[4][2][728]; // per-wave, per-pair cc row

  for (int f = tid; f < NF; f += 256) r1c[f] = Rc[((size_t)(b * C_ + c1)) * NF + f];
  for (int i = tid; i < 81; i += 256) { int a = i / 9, c = i % 9; t9[i] = wtab_g[80 * ((a * c) % 9)]; }
  for (int i = tid; i < 45; i += 256) { int bb = i / 9, c = i % 9; t45[i] = wtab_g[16 * bb * c]; }
  __syncthreads();                   // the only block-wide barrier

  const float SCALE = 1.0f / 518400.0f;   // 1/720^2

  for (int it = 0; it < 2; ++it) {
    const int c2A = c2base + (wid << 2) + 2 * it;    // pair A; pair B = c2A+1
    if (c2A + 1 < c1) continue;      // both pairs below diagonal: nothing would be emitted
    const float2* R2A = Rc + ((size_t)(b * C_ + c2A)) * NF;   // L2-hot after swizzle
    const float2* R2B = R2A + NF;

    // ---- stage 1: Z on the fly (both pairs, shared r1c/twiddles) + DFT-8 + exact W360 twiddle.
    if (lane < 45) {
      const int K2 = lane;
      float2 zinA[8], zinB[8];
#pragma unroll
      for (int q1 = 0; q1 < 8; ++q1) {
        const int k = 45 * q1 + K2;              // in [0, 360)
        const int fB = 360 - k;                  // in [1, 360]
        const float2 a1 = r1c[k];
        const float2 a2 = r1c[fB];
        const float2 w  = wtab_g[k];
        // pair A
        {
          const float2 b1 = R2A[k];
          const float2 b2 = R2A[fB];
          const float2 pA = make_float2(a1.x*b1.x + a1.y*b1.y, a1.y*b1.x - a1.x*b1.y);
          float2 pB = make_float2(a2.x*b2.x + a2.y*b2.y, a2.y*b2.x - a2.x*b2.y);
          pB.y = (k == 0) ? pB.y : -pB.y;        // conj for k>=1
          const float2 E = make_float2(pA.x + pB.x, pA.y + pB.y);
          const float2 O = make_float2(pA.x - pB.x, pA.y - pB.y);
          const float2 Ow = cmulp(O, w);
          zinA[q1] = make_float2(E.x - Ow.y, E.y + Ow.x);   // E + i*Ow
        }
        // pair B
        {
          const float2 b1 = R2B[k];
          const float2 b2 = R2B[fB];
          const float2 pA = make_float2(a1.x*b1.x + a1.y*b1.y, a1.y*b1.x - a1.x*b1.y);
          float2 pB = make_float2(a2.x*b2.x + a2.y*b2.y, a2.y*b2.x - a2.x*b2.y);
          pB.y = (k == 0) ? pB.y : -pB.y;
          const float2 E = make_float2(pA.x + pB.x, pA.y + pB.y);
          const float2 O = make_float2(pA.x - pB.x, pA.y - pB.y);
          const float2 Ow = cmulp(O, w);
          zinB[q1] = make_float2(E.x - Ow.y, E.y + Ow.x);
        }
      }
      float2 XA[8], XB[8];
      dft8_pos(zinA, XA);
      dft8_pos(zinB, XB);
      int m = 0;                                   // m = 2*K2*n1 <= 616: no mod needed
#pragma unroll
      for (int n1 = 0; n1 < 8; ++n1) {
        const float2 w = wtab_g[m];                // shared between pairs
        Yw[wid][0][n1 * 45 + K2] = cmulp(XA[n1], w);
        Yw[wid][1][n1 * 45 + K2] = cmulp(XB[n1], w);
        m += 2 * K2;
      }
    }
    WSYNC();   // my wave's Yw writes visible to my wave's stage-2 reads

    // ---- stage 2: DFT-45 per n1-row (9x5 CT), complex out; t9/t45 read from LDS (broadcast).
    {
      const int n1 = lane >> 3;
      const int cq = lane & 7;
      const int nci = (cq == 0) ? 2 : 1;
      int cvals[2] = { cq, 8 };

#pragma unroll
      for (int pp = 0; pp < 2; ++pp) {
        const float2* Yrow = &Yw[wid][pp][n1 * 45];
        float yr[2][5], yi[2][5];
#pragma unroll
        for (int ci = 0; ci < 2; ++ci)
#pragma unroll
          for (int d = 0; d < 5; ++d) { yr[ci][d] = 0.f; yi[ci][d] = 0.f; }

#pragma unroll
        for (int bq = 0; bq < 5; ++bq) {
          float2 z[9];
#pragma unroll
          for (int a = 0; a < 9; ++a) z[a] = Yrow[5 * a + bq];
#pragma unroll
          for (int ci = 0; ci < 2; ++ci) if (ci < nci) {
            const int c = cvals[ci];
            float ur = 0.f, ui = 0.f;
#pragma unroll
            for (int a = 0; a < 9; ++a) {
              const float2 t = t9[9 * a + c];
              ur += z[a].x * t.x - z[a].y * t.y;
              ui += z[a].x * t.y + z[a].y * t.x;
            }
            const float2 tw = t45[9 * bq + c];
            const float vr = ur * tw.x - ui * tw.y;
            const float vi = ur * tw.y + ui * tw.x;
#pragma unroll
            for (int d = 0; d < 5; ++d) {
              const int m = (bq * d) % 5;                   // compile-time
              yr[ci][d] += vr * W5X[m] - vi * W5Y[m];
              yi[ci][d] += vr * W5Y[m] + vi * W5X[m];
            }
          }
        }
        float2* cc2 = (float2*)(&ccw[wid][pp][0]);
#pragma unroll
        for (int ci = 0; ci < 2; ++ci) if (ci < nci) {
          const int c = cvals[ci];
#pragma unroll
          for (int d = 0; d < 5; ++d) {
            const int n2 = c + 9 * d;
            cc2[n1 + 8 * n2] = make_float2(yr[ci][d], yi[ci][d]);   // cc[2n], cc[2n+1]
          }
        }
      }
    }
    WSYNC();   // ccw writes visible to my wave's scans

    // ---- merged peak scans, half-wave per row (lanes 0-31: pair A, 32-63: pair B).
    {
      const int half = lane >> 5, sl = lane & 31;
      const int c2h = c2A + half;
      const float* cr = ccw[wid][half];
      float bvF = 0.f; int btF = 1;
      float bvM = 0.f; int uM  = 719;      // -> t' = 1 on all-zero
      for (int i = sl; i < 719; i += 32) {
        const int u = i + 1;               // 1..719
        const float v  = fabsf(cr[u]);
        const float lf = fabsf(cr[u - 1]);
        const float rt = fabsf(cr[(u == 719) ? 0 : (u + 1)]);
        if (v >= lf && v >= rt) {
          if (u <= 718 && (v > bvF || (v == bvF && u < btF))) { bvF = v; btF = u; }
          if (u >= 2   && (v > bvM || (v == bvM && u > uM)))  { bvM = v; uM  = u; }
        }
      }
      for (int off = 16; off; off >>= 1) {
        const float ovF = __shfl_down(bvF, off, 32); const int otF = __shfl_down(btF, off, 32);
        if (ovF > bvF || (ovF == bvF && otF < btF)) { bvF = ovF; btF = otF; }
        const float ovM = __shfl_down(bvM, off, 32); const int ouM = __shfl_down(uM, off, 32);
        if (ovM > bvM || (ovM == bvM && ouM > uM)) { bvM = ovM; uM = ouM; }
      }
      if (sl == 0 && c2h >= c1) {
        const float rF = (bvF > 0.f) ? cr[btF] * SCALE : 0.f;
        const size_t o = ((size_t)(b * C_ + c1)) * C_ + c2h;
        r_arr[o] = rF; t_arr[o] = btF;
        if (c2h > c1) {
          const float rM = (bvM > 0.f) ? cr[uM] * SCALE : 0.f;
          const size_t o2 = ((size_t)(b * C_ + c2h)) * C_ + c1;
          r_arr[o2] = rM; t_arr[o2] = 720 - uM;
        }
      }
    }
    WSYNC();   // scans' ccw reads done before next it overwrites
  }
}

// ---------------------------------------------------------------- K34: leaders/softmax/filt + spectral mix + output (fused; filt/leads stay in LDS)
__global__ __launch_bounds__(256) void k34_fused(const float* __restrict__ x,
                                                 const float* __restrict__ temperature,
                                                 const float* __restrict__ cls_w,
                                                 const float* __restrict__ basic_state,
                                                 const float* __restrict__ state_bias,
                                                 const float* __restrict__ mhw,
                                                 const float* __restrict__ mhb,
                                                 const float* __restrict__ r_arr,
                                                 const int* __restrict__ t_arr,
                                                 const float* __restrict__ seq,
                                                 const float* __restrict__ mu_g,
                                                 const float* __restrict__ std_g,
                                                 const float* __restrict__ mwr,
                                                 const float* __restrict__ mwi,
                                                 const float* __restrict__ mbr,
                                                 const float* __restrict__ mbi,
                                                 float* __restrict__ out) {
  const int bc = blockIdx.x;
  const int b = bc >> 7, c = bc & 127;
  const int tid = threadIdx.x;
  __shared__ float caL[C_], rL[C_];
  __shared__ int tL[C_];
  __shared__ float xrowL[L_];
  __shared__ float cfL[K_], srL[K_], pL[S_], qL[S_ * K_], praw[S_];
  __shared__ int leadL[K_], ltL[K_];
  __shared__ float cosT[96], sinT[96];
  __shared__ float ssL[K_][H_], ynL[H_], flL[OUT_];
  __shared__ float sfr[K_][F2_], sfi[K_][F2_], yfr[F2_], yfi[F2_];
  __shared__ float catr[3 * F2_], cati[3 * F2_], ofr[F2_], ofi[F2_];

  // ---- gather inputs (k3 part + k4 tables)
  const float* xb = x + (size_t)b * L_ * C_ + c;
  for (int l = tid; l < L_; l += 256) xrowL[l] = xb[(size_t)l * C_];
  if (tid < C_) {
    const float r = r_arr[(size_t)bc * C_ + tid];
    rL[tid] = r; caL[tid] = fabsf(r);
    tL[tid] = t_arr[(size_t)bc * C_ + tid];
  }
  if (tid >= 128 && tid < 224) {
    const int h = tid - 128;
    const float ang = (float)h * (float)(6.283185307179586 / 96.0);
    cosT[h] = cosf(ang); sinT[h] = sinf(ang);
    ynL[h] = seq[(size_t)bc * SEQLEN + L_ + h];
  }
  __syncthreads();

  // ---- top-k leaders + corr softmax (serial, tiny)
  if (tid == 0) {
    const float T = temperature[0];
    float lg[K_ + 1];
    lg[0] = 1.0f / T;
    for (int k = 0; k < K_; ++k) {       // stable top-k: strict > keeps smallest index on ties
      float bvv = -1.f; int bi = 0;
      for (int jj = 0; jj < C_; ++jj) { const float v = caL[jj]; if (v > bvv) { bvv = v; bi = jj; } }
      leadL[k] = bi; ltL[k] = tL[bi];
      const float rv = rL[bi];
      srL[k] = (rv > 0.f) ? 1.f : ((rv < 0.f) ? -1.f : 0.f);
      lg[k + 1] = bvv / T;
      caL[bi] = -2.f;
    }
    float m = lg[0];
    for (int k = 1; k <= K_; ++k) m = fmaxf(m, lg[k]);
    float sum = 0.f, e[K_ + 1];
    for (int k = 0; k <= K_; ++k) { e[k] = expf(lg[k] - m); sum += e[k]; }
    const float invs = 1.0f / sum;
    for (int k = 0; k < K_; ++k) cfL[k] = e[k + 1] * invs;
  }

  // ---- p logits: 8 groups of 32 lanes
  {
    const int gg = tid >> 5, lane = tid & 31;
    float acc = 0.f;
    const float* w = cls_w + (size_t)gg * L_;
    for (int l = lane; l < L_; l += 32) acc += xrowL[l] * w[l];
    for (int off = 16; off; off >>= 1) acc += __shfl_down(acc, off, 32);
    if (lane == 0) praw[gg] = acc + state_bias[gg] + basic_state[c * S_ + gg];
  }
  __syncthreads();
  if (tid == 0) {
    float m = praw[0];
    for (int s2 = 1; s2 < S_; ++s2) m = fmaxf(m, praw[s2]);
    float sum = 0.f;
    for (int s2 = 0; s2 < S_; ++s2) { const float e = expf(praw[s2] - m); pL[s2] = e; sum += e; }
    const float invs = 1.0f / sum;
    for (int s2 = 0; s2 < S_; ++s2) pL[s2] *= invs;
    for (int s2 = 0; s2 < S_; ++s2)
      for (int k = 0; k < K_; ++k) qL[s2 * K_ + k] = pL[s2] * cfL[k];
  }
  __syncthreads();

  // ---- filt -> LDS; leader window gather (both depend on step above)
  for (int o = tid; o < OUT_; o += 256) {
    float acc = 0.f;
#pragma unroll
    for (int s2 = 0; s2 < S_; ++s2) {
      acc += pL[s2] * mhb[s2 * OUT_ + o];
#pragma unroll
      for (int k = 0; k < K_; ++k)
        acc += qL[s2 * K_ + k] * mhw[(size_t)s2 * (K_ * OUT_) + k * OUT_ + o];
    }
    flL[o] = acc;
  }
  for (int i = tid; i < K_ * H_; i += 256) {
    const int k = i / H_, h = i - k * H_;
    ssL[k][h] = seq[((size_t)(b * C_ + leadL[k])) * SEQLEN + (L_ + h - ltL[k])] * srL[k];
  }
  __syncthreads();

  // ---- 96-pt rfft (DFT) of ss rows and yn
  for (int u = tid; u < K_ * F2_ + F2_; u += 256) {
    if (u < K_ * F2_) {
      const int k = u / F2_, f = u - k * F2_;
      float re = 0.f, im = 0.f; int m = 0;
      for (int h = 0; h < H_; ++h) {
        const float v = ssL[k][h];
        re = fmaf(v, cosT[m], re); im = fmaf(-v, sinT[m], im);
        m += f; if (m >= 96) m -= 96;
      }
      sfr[k][f] = re; sfi[k][f] = im;
    } else {
      const int f = u - K_ * F2_;
      float re = 0.f, im = 0.f; int m = 0;
      for (int h = 0; h < H_; ++h) {
        const float v = ynL[h];
        re = fmaf(v, cosT[m], re); im = fmaf(-v, sinT[m], im);
        m += f; if (m >= 96) m -= 96;
      }
      yfr[f] = re; yfi[f] = im;
    }
  }
  __syncthreads();

  if (tid < F2_) {
    const int f = tid;
    float s1r = 0.f, s1i = 0.f, s2r = 0.f, s2i = 0.f;
    const float yr = yfr[f], yi = yfi[f];
#pragma unroll
    for (int k = 0; k < K_; ++k) {
      const float fa = flL[k * F2_ + f], fb = flL[(K_ + k) * F2_ + f];
      const float ar = sfr[k][f] * fa, ai = sfi[k][f] * fa;
      s1r += ar; s1i += ai;
      s2r += (ar - yr) * fb; s2i += (ai - yi) * fb;
    }
    const float fc = flL[2 * K_ * F2_ + f];
    catr[f] = s1r;            cati[f] = s1i;
    catr[F2_ + f] = s2r;      cati[F2_ + f] = s2i;
    catr[2 * F2_ + f] = yr * fc; cati[2 * F2_ + f] = yi * fc;
  }
  __syncthreads();

  if (tid < F2_) {
    const int o = tid;
    float ar = mbr[o], ai = mbi[o];
    const float* wr = mwr + (size_t)o * (3 * F2_);
    const float* wi = mwi + (size_t)o * (3 * F2_);
    for (int f = 0; f < 3 * F2_; ++f) {
      const float cr = catr[f], ci = cati[f];
      const float wrr = wr[f], wii = wi[f];
      ar += cr * wrr - ci * wii;
      ai += cr * wii + ci * wrr;
    }
    ofr[o] = ar; ofi[o] = ai;
  }
  __syncthreads();

  if (tid < H_) {
    const int h = tid;
    float val = ofr[0] + ofr[48] * ((h & 1) ? -1.f : 1.f);
    int m = h;                                  // (f*h)%96 for f=1
    for (int f = 1; f < 48; ++f) {
      val += 2.f * (ofr[f] * cosT[m] - ofi[f] * sinT[m]);
      m += h; if (m >= 96) m -= 96;
    }
    val *= (1.0f / 96.0f);
    const float mu = mu_g[bc], stdv = std_g[bc];
    out[((size_t)b * H_ + h) * C_ + c] = (ynL[h] + val) * stdv + mu;
  }
}

// ---------------------------------------------------------------- launch
extern "C" void kernel_launch(void* const* d_in, const int* in_sizes, int n_in,
                              void* d_out, int out_size, void* d_ws, size_t ws_size,
                              hipStream_t stream) {
  const float* x    = (const float*)d_in[0];
  const float* yh   = (const float*)d_in[1];
  const float* temp = (const float*)d_in[2];
  const float* clsw = (const float*)d_in[3];
  const float* bst  = (const float*)d_in[4];
  const float* sbias= (const float*)d_in[5];
  const float* mhw  = (const float*)d_in[6];
  const float* mhb  = (const float*)d_in[7];
  const float* mwr  = (const float*)d_in[8];
  const float* mwi  = (const float*)d_in[9];
  const float* mbr  = (const float*)d_in[10];
  const float* mbi  = (const float*)d_in[11];
  float* out = (float*)d_out;

  float* ws = (float*)d_ws;
  float* seq    = ws;                                   // 2048*816
  float* mu_g   = seq + (size_t)2048 * SEQLEN;          // 2048
  float* std_g  = mu_g + 2048;                          // 2048
  float* r_arr  = std_g + 2048;                         // 262144
  int*   t_arr  = (int*)(r_arr + (size_t)2048 * C_);    // 262144
  float2* Rc    = (float2*)(t_arr + (size_t)2048 * C_); // 2048*361 float2
  float2* wtab  = Rc + (size_t)2048 * NF;               // 720 float2

  hipLaunchKernelGGL(k0_tab, dim3(1), dim3(256), 0, stream, wtab);
  hipLaunchKernelGGL(k1_fused, dim3(B_ * C_ / 2), dim3(256), 0, stream, x, yh, wtab, seq, mu_g, std_g, Rc);
  hipLaunchKernelGGL(k2_fft, dim3(B_ * 576), dim3(256), 0, stream, Rc, wtab, r_arr, t_arr);
  hipLaunchKernelGGL(k34_fused, dim3(B_ * C_), dim3(256), 0, stream,
                     x, temp, clsw, bst, sbias, mhw, mhb, r_arr, t_arr,
                     seq, mu_g, std_g, mwr, mwi, mbr, mbi, out);
}